// Round 1
// baseline (47.675 us; speedup 1.0000x reference)
//
#include <hip/hip_runtime.h>

#define NB 1024
#define ND 256
#define APB 4            // anchors per block
#define NBLK (NB/APB)    // 256 blocks
#define NTHR 256
#define MARGINF 0.3f
#define BIGV 1e9f
#define D2R 0.017453292519943295f

// haversine 'a' thresholds: sin^2(T / (2*6371000)), computed in double offline
#define A_POS 3.8495040e-12f   // T = 25 m
#define A_NEG 6.1592064e-11f   // T = 100 m

__global__ __launch_bounds__(NTHR) void triplet_main(
    const float* __restrict__ emb, const float* __restrict__ gps,
    float* __restrict__ tri, float* __restrict__ val)
{
    __shared__ float4 sA[APB][ND/4];   // 4 KB anchor embeddings
    __shared__ float  sSA[APB];
    __shared__ float  wmax[4][APB];
    __shared__ float  wmin[4][APB];

    const int tid  = threadIdx.x;
    const int lane = tid & 63;
    const int wave = tid >> 6;
    const int i0   = blockIdx.x * APB;

    // stage 4 anchor rows (coalesced: 256 float4 = 4*256 floats)
    sA[wave][lane] = ((const float4*)emb)[i0*(ND/4) + tid];
    __syncthreads();

    // anchor squared norms: wave w reduces anchor w
    {
        float4 v = sA[wave][lane];
        float p = v.x*v.x + v.y*v.y + v.z*v.z + v.w*v.w;
        #pragma unroll
        for (int off = 32; off; off >>= 1) p += __shfl_xor(p, off);
        if (lane == 0) sSA[wave] = p;
    }

    // anchor gps scalars
    float latA[APB], lonA[APB], cosA[APB];
    #pragma unroll
    for (int a = 0; a < APB; ++a) {
        latA[a] = gps[(i0+a)*2];
        lonA[a] = gps[(i0+a)*2+1];
        cosA[a] = cosf(latA[a] * D2R);
    }
    __syncthreads();
    float SA[APB];
    #pragma unroll
    for (int a = 0; a < APB; ++a) SA[a] = sSA[a];

    float pmax[APB], nmin[APB], smin[APB];
    #pragma unroll
    for (int a = 0; a < APB; ++a) { pmax[a] = -1.f; nmin[a] = BIGV; smin[a] = BIGV; }

    float dsv[4][APB];          // all 16 pair-distances live in registers
    unsigned int negbits = 0;

    #pragma unroll
    for (int g = 0; g < 4; ++g) {
        const int j = (g << 8) + tid;
        const float4* __restrict__ row = (const float4*)(emb + (size_t)j * ND);
        float acc[APB] = {0.f, 0.f, 0.f, 0.f};
        float sq = 0.f;
        #pragma unroll 8
        for (int k = 0; k < ND/4; ++k) {
            float4 v = row[k];
            sq = fmaf(v.x,v.x, fmaf(v.y,v.y, fmaf(v.z,v.z, fmaf(v.w,v.w, sq))));
            #pragma unroll
            for (int a = 0; a < APB; ++a) {
                float4 e = sA[a][k];   // LDS broadcast (all lanes same addr)
                acc[a] = fmaf(v.x,e.x, fmaf(v.y,e.y, fmaf(v.z,e.z, fmaf(v.w,e.w, acc[a]))));
            }
        }
        float latj = gps[2*j], lonj = gps[2*j+1];
        float cosj = cosf(latj * D2R);
        #pragma unroll
        for (int a = 0; a < APB; ++a) {
            float d2 = SA[a] + sq - 2.f*acc[a];
            float d  = d2 > 0.f ? sqrtf(d2) : 0.f;
            float sla = sinf((latj - latA[a]) * (0.5f*D2R));
            float slo = sinf((lonj - lonA[a]) * (0.5f*D2R));
            float hav = fmaf(sla, sla, cosA[a]*cosj*slo*slo);
            bool pos = (hav < A_POS) && (j != i0 + a);
            bool neg = (hav > A_NEG);
            if (pos) pmax[a] = fmaxf(pmax[a], d);
            if (neg) { nmin[a] = fminf(nmin[a], d); negbits |= (1u << (g*APB + a)); }
            dsv[g][a] = d;
        }
    }

    // block-wide per-anchor reductions: max(pmax), min(nmin)
    #pragma unroll
    for (int a = 0; a < APB; ++a) {
        #pragma unroll
        for (int off = 32; off; off >>= 1) {
            pmax[a] = fmaxf(pmax[a], __shfl_xor(pmax[a], off));
            nmin[a] = fminf(nmin[a], __shfl_xor(nmin[a], off));
        }
    }
    if (lane == 0) {
        #pragma unroll
        for (int a = 0; a < APB; ++a) { wmax[wave][a] = pmax[a]; wmin[wave][a] = nmin[a]; }
    }
    __syncthreads();
    float dap[APB], negmin[APB];
    #pragma unroll
    for (int a = 0; a < APB; ++a) {
        dap[a]    = fmaxf(fmaxf(wmax[0][a], wmax[1][a]), fmaxf(wmax[2][a], wmax[3][a]));
        negmin[a] = fminf(fminf(wmin[0][a], wmin[1][a]), fminf(wmin[2][a], wmin[3][a]));
    }

    // semi-hard pass entirely in registers
    #pragma unroll
    for (int g = 0; g < 4; ++g) {
        #pragma unroll
        for (int a = 0; a < APB; ++a) {
            float d = dsv[g][a];
            if (((negbits >> (g*APB + a)) & 1u) && d > dap[a] && d < dap[a] + MARGINF)
                smin[a] = fminf(smin[a], d);
        }
    }
    #pragma unroll
    for (int a = 0; a < APB; ++a) {
        #pragma unroll
        for (int off = 32; off; off >>= 1) smin[a] = fminf(smin[a], __shfl_xor(smin[a], off));
    }
    __syncthreads();   // done reading wmin for negmin
    if (lane == 0) {
        #pragma unroll
        for (int a = 0; a < APB; ++a) wmin[wave][a] = smin[a];
    }
    __syncthreads();

    if (tid < APB) {
        const int a = tid;
        float semi = fminf(fminf(wmin[0][a], wmin[1][a]), fminf(wmin[2][a], wmin[3][a]));
        bool has_pos  = dap[a] > -0.5f;
        bool has_neg  = negmin[a] < 0.5f*BIGV;
        bool has_semi = semi < 0.5f*BIGV;
        float dan = has_semi ? semi : negmin[a];
        bool valid = has_pos && has_neg;
        float t = dap[a] - dan + MARGINF;
        t = t > 0.f ? t : 0.f;
        tri[i0+a] = valid ? t : 0.f;
        val[i0+a] = valid ? 1.f : 0.f;
    }
}

__global__ __launch_bounds__(256) void triplet_final(
    const float* __restrict__ tri, const float* __restrict__ val, float* __restrict__ out)
{
    const int tid = threadIdx.x;
    float st = 0.f, sv = 0.f;
    #pragma unroll
    for (int g = 0; g < 4; ++g) { st += tri[tid + (g<<8)]; sv += val[tid + (g<<8)]; }
    #pragma unroll
    for (int off = 32; off; off >>= 1) { st += __shfl_xor(st, off); sv += __shfl_xor(sv, off); }
    __shared__ float rt[4], rv[4];
    if ((tid & 63) == 0) { rt[tid>>6] = st; rv[tid>>6] = sv; }
    __syncthreads();
    if (tid == 0) {
        float t = rt[0]+rt[1]+rt[2]+rt[3];
        float v = rv[0]+rv[1]+rv[2]+rv[3];
        out[0] = t / fmaxf(v, 1.f);
    }
}

extern "C" void kernel_launch(void* const* d_in, const int* in_sizes, int n_in,
                              void* d_out, int out_size, void* d_ws, size_t ws_size,
                              hipStream_t stream) {
    const float* emb = (const float*)d_in[0];   // [1024,256] f32
    const float* gps = (const float*)d_in[1];   // [1024,2]  f32
    float* tri = (float*)d_ws;                  // [1024]
    float* val = tri + NB;                      // [1024]
    triplet_main<<<NBLK, NTHR, 0, stream>>>(emb, gps, tri, val);
    triplet_final<<<1, 256, 0, stream>>>(tri, val, (float*)d_out);
}

// Round 2
// 44.018 us; speedup vs baseline: 1.0831x; 1.0831x over previous
//
#include <hip/hip_runtime.h>

#define NB 1024
#define ND 256
#define APB 4            // anchors per block
#define NBLK (NB/APB)    // 256 blocks (1 per CU)
#define NTHR 1024        // 16 waves per block -> 4 waves/SIMD
#define NWAVE (NTHR/64)
#define MARGINF 0.3f
#define BIGV 1e9f
#define D2R 0.017453292519943295f

// haversine 'a' thresholds: sin^2(T / (2*6371000)), computed in double offline
#define A_POS 3.8495040e-12f   // T = 25 m
#define A_NEG 6.1592064e-11f   // T = 100 m

__global__ __launch_bounds__(NTHR, 4) void triplet_main(
    const float* __restrict__ emb, const float* __restrict__ gps,
    float* __restrict__ tri, float* __restrict__ val)
{
    __shared__ float4 sA[APB][ND/4];        // 4 KB anchor embeddings
    __shared__ float  sSA[APB];
    __shared__ float  wmax[NWAVE][APB];     // 16x4
    __shared__ float  wmin[NWAVE][APB];
    __shared__ float  wsmin[NWAVE][APB];
    __shared__ float  sdap[APB], sneg[APB];

    const int tid  = threadIdx.x;
    const int lane = tid & 63;
    const int wave = tid >> 6;
    const int i0   = blockIdx.x * APB;
    const int j    = tid;                   // each thread owns one j-row

    // stage anchors (first 256 threads, coalesced)
    if (tid < APB*(ND/4))
        ((float4*)sA)[tid] = ((const float4*)emb)[i0*(ND/4) + tid];

    // anchor gps (wave-uniform scalar loads)
    float latA[APB], lonA[APB], cosA[APB];
    #pragma unroll
    for (int a = 0; a < APB; ++a) {
        latA[a] = gps[(i0+a)*2];
        lonA[a] = gps[(i0+a)*2+1];
        cosA[a] = cosf(latA[a] * D2R);
    }
    __syncthreads();

    // one j-row per thread: 64 k-chunks, 4 LDS broadcasts + 1 global float4 each
    const float4* __restrict__ row = (const float4*)(emb + (size_t)j * ND);
    float acc[APB] = {0.f, 0.f, 0.f, 0.f};
    float sq = 0.f;
    #pragma unroll 8
    for (int k = 0; k < ND/4; ++k) {
        float4 v = row[k];
        sq = fmaf(v.x,v.x, fmaf(v.y,v.y, fmaf(v.z,v.z, fmaf(v.w,v.w, sq))));
        #pragma unroll
        for (int a = 0; a < APB; ++a) {
            float4 e = sA[a][k];
            acc[a] = fmaf(v.x,e.x, fmaf(v.y,e.y, fmaf(v.z,e.z, fmaf(v.w,e.w, acc[a]))));
        }
    }

    // thread whose row IS anchor a donates its squared norm
    unsigned rel = (unsigned)(j - i0);
    if (rel < (unsigned)APB) sSA[rel] = sq;
    __syncthreads();

    const float latj = gps[2*j], lonj = gps[2*j+1];
    const float cosj = cosf(latj * D2R);

    float dsv[APB], pmax[APB], nmin[APB];
    unsigned negbits = 0;
    #pragma unroll
    for (int a = 0; a < APB; ++a) {
        float d2 = sSA[a] + sq - 2.f*acc[a];
        float d  = d2 > 0.f ? sqrtf(d2) : 0.f;
        float sla = sinf((latj - latA[a]) * (0.5f*D2R));
        float slo = sinf((lonj - lonA[a]) * (0.5f*D2R));
        float hav = fmaf(sla, sla, cosA[a]*cosj*slo*slo);
        bool pos = (hav < A_POS) && (j != i0 + a);
        bool neg = (hav > A_NEG);
        pmax[a] = pos ? d : -1.f;
        nmin[a] = neg ? d : BIGV;
        if (neg) negbits |= (1u << a);
        dsv[a] = d;
    }

    // wave-level reduce pmax/nmin
    #pragma unroll
    for (int a = 0; a < APB; ++a) {
        #pragma unroll
        for (int off = 32; off; off >>= 1) {
            pmax[a] = fmaxf(pmax[a], __shfl_xor(pmax[a], off));
            nmin[a] = fminf(nmin[a], __shfl_xor(nmin[a], off));
        }
    }
    if (lane == 0) {
        #pragma unroll
        for (int a = 0; a < APB; ++a) { wmax[wave][a] = pmax[a]; wmin[wave][a] = nmin[a]; }
    }
    __syncthreads();

    // wave 0: reduce [16][4] via lane mapping lane = w*4 + a (lanes 0..63)
    if (wave == 0) {
        float vmax = wmax[lane >> 2][lane & 3];
        float vmin = wmin[lane >> 2][lane & 3];
        #pragma unroll
        for (int off = 4; off < 64; off <<= 1) {
            vmax = fmaxf(vmax, __shfl_xor(vmax, off));
            vmin = fminf(vmin, __shfl_xor(vmin, off));
        }
        if (lane < APB) { sdap[lane] = vmax; sneg[lane] = vmin; }
    }
    __syncthreads();

    // semi-hard pass in registers
    float smin[APB];
    #pragma unroll
    for (int a = 0; a < APB; ++a) {
        float dap = sdap[a];
        float d = dsv[a];
        bool semi = ((negbits >> a) & 1u) && d > dap && d < dap + MARGINF;
        smin[a] = semi ? d : BIGV;
        #pragma unroll
        for (int off = 32; off; off >>= 1)
            smin[a] = fminf(smin[a], __shfl_xor(smin[a], off));
    }
    if (lane == 0) {
        #pragma unroll
        for (int a = 0; a < APB; ++a) wsmin[wave][a] = smin[a];
    }
    __syncthreads();

    if (wave == 0) {
        float vs = wsmin[lane >> 2][lane & 3];
        #pragma unroll
        for (int off = 4; off < 64; off <<= 1) vs = fminf(vs, __shfl_xor(vs, off));
        if (lane < APB) {
            const int a = lane;
            float dap    = sdap[a];
            float negmin = sneg[a];
            bool has_pos  = dap > -0.5f;
            bool has_neg  = negmin < 0.5f*BIGV;
            bool has_semi = vs < 0.5f*BIGV;
            float dan = has_semi ? vs : negmin;
            bool valid = has_pos && has_neg;
            float t = dap - dan + MARGINF;
            t = t > 0.f ? t : 0.f;
            tri[i0+a] = valid ? t : 0.f;
            val[i0+a] = valid ? 1.f : 0.f;
        }
    }
}

__global__ __launch_bounds__(256) void triplet_final(
    const float* __restrict__ tri, const float* __restrict__ val, float* __restrict__ out)
{
    const int tid = threadIdx.x;
    float st = 0.f, sv = 0.f;
    #pragma unroll
    for (int g = 0; g < 4; ++g) { st += tri[tid + (g<<8)]; sv += val[tid + (g<<8)]; }
    #pragma unroll
    for (int off = 32; off; off >>= 1) { st += __shfl_xor(st, off); sv += __shfl_xor(sv, off); }
    __shared__ float rt[4], rv[4];
    if ((tid & 63) == 0) { rt[tid>>6] = st; rv[tid>>6] = sv; }
    __syncthreads();
    if (tid == 0) {
        float t = rt[0]+rt[1]+rt[2]+rt[3];
        float v = rv[0]+rv[1]+rv[2]+rv[3];
        out[0] = t / fmaxf(v, 1.f);
    }
}

extern "C" void kernel_launch(void* const* d_in, const int* in_sizes, int n_in,
                              void* d_out, int out_size, void* d_ws, size_t ws_size,
                              hipStream_t stream) {
    const float* emb = (const float*)d_in[0];   // [1024,256] f32
    const float* gps = (const float*)d_in[1];   // [1024,2]  f32
    float* tri = (float*)d_ws;                  // [1024]
    float* val = tri + NB;                      // [1024]
    triplet_main<<<NBLK, NTHR, 0, stream>>>(emb, gps, tri, val);
    triplet_final<<<1, 256, 0, stream>>>(tri, val, (float*)d_out);
}